// Round 5
// baseline (238.567 us; speedup 1.0000x reference)
//
#include <hip/hip_runtime.h>

#define NS 8192
#define EMBED 128
#define COLCHUNK 1024            // grid.y = 8 chunks of 1024 cols
#define AROW 12                  // adj-hist row stride (11 bins + 1 pad)
#define INV64K (1.0f / 65536.0f)

typedef __bf16 bf16x8 __attribute__((ext_vector_type(8)));
typedef float f32x4 __attribute__((ext_vector_type(4)));

// workspace layout (bytes from ws start)
#define OFF_XB  0u               // bf16 [8192][128] = 2 MiB
#define OFF_GS  2097152u         // fp32 [8192][4]   cumulative C bins 3..6
#define OFF_GSP 2228224u         // fp32 [8192][4]   cumulative Cp bins 3..6
#define OFF_GA  2359296u         // i32  [8192][12]  all-hist corrections (q16)
#define OFF_GAP 2752512u         // i32  [8192][12]  pos-hist corrections (q16)
#define OFF_CC  3145728u         // int  [128] class counts
#define OFF_AC  3146240u         // float[2] accum + u32 done
#define ZERO_BYTES 1049120u      // OFF_GS .. end (16B multiple)

__device__ inline unsigned short f2bf(float f) {
  unsigned u = __float_as_uint(f);
  u += 0x7fffu + ((u >> 16) & 1u);   // round-to-nearest-even
  return (unsigned short)(u >> 16);
}
__device__ inline float clamp01(float x) { return fminf(fmaxf(x, 0.f), 1.f); }

// ---- prep: fp32->bf16 convert + zero all accumulator regions ----
__global__ __launch_bounds__(256) void prep_kernel(const float* __restrict__ x,
                                                   unsigned short* __restrict__ xb,
                                                   uint4* __restrict__ zbase) {
  const int gid = blockIdx.x * 256 + threadIdx.x;   // grid covers 8192*128/4
  float4 v = reinterpret_cast<const float4*>(x)[gid];
  ushort4 o;
  o.x = f2bf(v.x); o.y = f2bf(v.y); o.z = f2bf(v.z); o.w = f2bf(v.w);
  reinterpret_cast<ushort4*>(xb)[gid] = o;
  if (gid < (int)(ZERO_BYTES / 16u)) zbase[gid] = make_uint4(0u, 0u, 0u, 0u);
}

// per-tile epilogue: u = t-5; exact register bins 3..6 (cumulative),
// rare |u|>2 lanes (incl. diagonal) write q16 corrections to LDS.
__device__ __forceinline__ void tile_epilogue(
    const f32x4& acc0, const f32x4& acc1, int j, int labj,
    const int* labi, const int* iRow, int rl0,
    float (&C)[4][4], float (&Cp)[4][4],
    unsigned* sHs, unsigned* sHsp) {
  #pragma unroll
  for (int r = 0; r < 4; ++r) {
    const float u = -5.f * (acc0[r] + acc1[r]);     // u = t - 5
    const bool isPos = (labi[r] == labj) & (iRow[r] != j);
    const float pm = isPos ? 1.f : 0.f;
    const float d0 = clamp01(-1.f - u);   // bin 3
    const float d1 = clamp01( 0.f - u);   // bin 4
    const float d2 = clamp01( 1.f - u);   // bin 5
    const float d3 = clamp01( 2.f - u);   // bin 6
    C[r][0] += d0; C[r][1] += d1; C[r][2] += d2; C[r][3] += d3;
    Cp[r][0] = fmaf(pm, d0, Cp[r][0]);
    Cp[r][1] = fmaf(pm, d1, Cp[r][1]);
    Cp[r][2] = fmaf(pm, d2, Cp[r][2]);
    Cp[r][3] = fmaf(pm, d3, Cp[r][3]);

    if (fabsf(u) > 2.f) {                // rare: outlier or diagonal
      const int row = rl0 + r;
      if (iRow[r] == j) {
        // diagonal: cancel fast contributions and the bins>=7 base (+1)
        C[r][0] -= d0; C[r][1] -= d1; C[r][2] -= d2; C[r][3] -= d3;
        #pragma unroll
        for (int k = 7; k <= 10; ++k)
          atomicAdd(&sHs[row * AROW + k], (unsigned)(-65536));
      } else {
        const float t = u + 5.f;
        #pragma unroll
        for (int k = 0; k <= 2; ++k) {   // assumed 0
          const float v = clamp01((float)(k + 1) - t);
          const int q = (int)(v * 65536.f + 0.5f);
          if (q) {
            atomicAdd(&sHs[row * AROW + k], (unsigned)q);
            if (isPos) atomicAdd(&sHsp[row * AROW + k], (unsigned)q);
          }
        }
        #pragma unroll
        for (int k = 7; k <= 10; ++k) {  // assumed 1
          const float v = clamp01((float)(k + 1) - t) - 1.f;
          const int q = (int)(v * 65536.f - 0.5f);
          if (q) {
            atomicAdd(&sHs[row * AROW + k], (unsigned)q);
            if (isPos) atomicAdd(&sHsp[row * AROW + k], (unsigned)q);
          }
        }
      }
    }
  }
}

// ---- main: dist2 MFMA + 4-bin cumulative register histogram, SW-pipelined ----
// Column loop unrolled x2 with two B-fragment register buffers; each buffer's
// refill (tile +32, AND-wrapped in-chunk) issues right after its MFMAs, giving
// each global load ~2 half-iterations of issue work (x4 waves) to return.
__global__ __launch_bounds__(256, 4) void fastap_main_kernel(
    const unsigned short* __restrict__ xb,
    const int* __restrict__ labels,
    float* __restrict__ gS, float* __restrict__ gSp,
    unsigned* __restrict__ gA, unsigned* __restrict__ gAp,
    int* __restrict__ ccount) {
  __shared__ int sLab[COLCHUNK];
  __shared__ unsigned sHs[64 * AROW];   // all-hist corrections (signed q16)
  __shared__ unsigned sHsp[64 * AROW];  // pos-hist corrections (signed q16)

  const int tid  = threadIdx.x;
  const int wave = tid >> 6;
  const int lane = tid & 63;
  const int l16  = lane & 15;
  const int quad = lane >> 4;
  const int rowBase  = blockIdx.x * 64;
  const int colBegin = blockIdx.y * COLCHUNK;
  const int rl0 = wave * 16 + quad * 4;   // first of this lane's 4 rows

  if (blockIdx.y == 0 && tid < 64) atomicAdd(&ccount[labels[rowBase + tid]], 1);

  reinterpret_cast<int4*>(sLab)[tid] =
      reinterpret_cast<const int4*>(labels + colBegin)[tid];
  for (int idx = tid; idx < 64 * AROW; idx += 256) { sHs[idx] = 0u; sHsp[idx] = 0u; }

  bf16x8 afr[4];
  const int arow = rowBase + wave * 16 + l16;
  #pragma unroll
  for (int kb = 0; kb < 4; ++kb)
    afr[kb] = *reinterpret_cast<const bf16x8*>(&xb[arow * EMBED + kb * 32 + quad * 8]);

  int labi[4], iRow[4];
  #pragma unroll
  for (int r = 0; r < 4; ++r) {
    iRow[r] = rowBase + rl0 + r;
    labi[r] = labels[iRow[r]];
  }

  float C[4][4], Cp[4][4];
  #pragma unroll
  for (int r = 0; r < 4; ++r)
    #pragma unroll
    for (int k = 0; k < 4; ++k) { C[r][k] = 0.f; Cp[r][k] = 0.f; }

  // prime two B buffers (tiles 0 and 16)
  const int bcol = l16 * EMBED + quad * 8;   // per-lane B offset within a tile
  bf16x8 b0[4], b1[4];
  #pragma unroll
  for (int kb = 0; kb < 4; ++kb) {
    b0[kb] = *reinterpret_cast<const bf16x8*>(&xb[colBegin * EMBED + bcol + kb * 32]);
    b1[kb] = *reinterpret_cast<const bf16x8*>(&xb[(colBegin + 16) * EMBED + bcol + kb * 32]);
  }

  __syncthreads();

  for (int c0 = 0; c0 < COLCHUNK; c0 += 32) {
    // ---- half-tile A: cols colBegin + c0, buffer b0 ----
    {
      f32x4 acc0 = {0.f, 0.f, 0.f, 0.f}, acc1 = {0.f, 0.f, 0.f, 0.f};
      acc0 = __builtin_amdgcn_mfma_f32_16x16x32_bf16(afr[0], b0[0], acc0, 0, 0, 0);
      acc0 = __builtin_amdgcn_mfma_f32_16x16x32_bf16(afr[1], b0[1], acc0, 0, 0, 0);
      acc1 = __builtin_amdgcn_mfma_f32_16x16x32_bf16(afr[2], b0[2], acc1, 0, 0, 0);
      acc1 = __builtin_amdgcn_mfma_f32_16x16x32_bf16(afr[3], b0[3], acc1, 0, 0, 0);
      // refill b0 with tile c0+32 (wrapped; tail prefetch is harmless dup)
      const int cp = colBegin + ((c0 + 32) & (COLCHUNK - 1));
      #pragma unroll
      for (int kb = 0; kb < 4; ++kb)
        b0[kb] = *reinterpret_cast<const bf16x8*>(&xb[cp * EMBED + bcol + kb * 32]);
      tile_epilogue(acc0, acc1, colBegin + c0 + l16, sLab[c0 + l16],
                    labi, iRow, rl0, C, Cp, sHs, sHsp);
    }
    // ---- half-tile B: cols colBegin + c0 + 16, buffer b1 ----
    {
      f32x4 acc0 = {0.f, 0.f, 0.f, 0.f}, acc1 = {0.f, 0.f, 0.f, 0.f};
      acc0 = __builtin_amdgcn_mfma_f32_16x16x32_bf16(afr[0], b1[0], acc0, 0, 0, 0);
      acc0 = __builtin_amdgcn_mfma_f32_16x16x32_bf16(afr[1], b1[1], acc0, 0, 0, 0);
      acc1 = __builtin_amdgcn_mfma_f32_16x16x32_bf16(afr[2], b1[2], acc1, 0, 0, 0);
      acc1 = __builtin_amdgcn_mfma_f32_16x16x32_bf16(afr[3], b1[3], acc1, 0, 0, 0);
      const int cp = colBegin + ((c0 + 48) & (COLCHUNK - 1));
      #pragma unroll
      for (int kb = 0; kb < 4; ++kb)
        b1[kb] = *reinterpret_cast<const bf16x8*>(&xb[cp * EMBED + bcol + kb * 32]);
      tile_epilogue(acc0, acc1, colBegin + c0 + 16 + l16, sLab[c0 + 16 + l16],
                    labi, iRow, rl0, C, Cp, sHs, sHsp);
    }
  }

  // butterfly-reduce C/Cp across the 16 lanes sharing each row
  #pragma unroll
  for (int m = 1; m < 16; m <<= 1)
    #pragma unroll
    for (int r = 0; r < 4; ++r)
      #pragma unroll
      for (int k = 0; k < 4; ++k) {
        C[r][k]  += __shfl_xor(C[r][k],  m, 64);
        Cp[r][k] += __shfl_xor(Cp[r][k], m, 64);
      }

  if (l16 == 0) {
    #pragma unroll
    for (int r = 0; r < 4; ++r)
      #pragma unroll
      for (int k = 0; k < 4; ++k) {
        atomicAdd(&gS[(rowBase + rl0 + r) * 4 + k],  C[r][k]);
        atomicAdd(&gSp[(rowBase + rl0 + r) * 4 + k], Cp[r][k]);
      }
  }

  __syncthreads();
  for (int idx = tid; idx < 64 * AROW; idx += 256) {
    const unsigned v = sHs[idx], vp = sHsp[idx];
    if (v)  atomicAdd(&gA[rowBase * AROW + idx], v);
    if (vp) atomicAdd(&gAp[rowBase * AROW + idx], vp);
  }
}

// ---- epilogue: per-row AP + final loss (last block finalizes) ----
__global__ __launch_bounds__(256) void epilogue_kernel(
    const float* __restrict__ gS, const float* __restrict__ gSp,
    const unsigned* __restrict__ gA, const unsigned* __restrict__ gAp,
    const int* __restrict__ labels, const int* __restrict__ ccount,
    float* __restrict__ accum, unsigned* __restrict__ done,
    float* __restrict__ out) {
  const int i = blockIdx.x * 256 + threadIdx.x;
  const int np = ccount[labels[i]] - 1;   // N_pos = classCount - 1
  float ap = 0.f, val = 0.f, HpPrev = 0.f;
  #pragma unroll
  for (int b = 0; b <= 10; ++b) {
    const float baseH  = (b < 3) ? 0.f : (b < 7) ? gS[i * 4 + (b - 3)]  : 8192.f;
    const float basePp = (b < 3) ? 0.f : (b < 7) ? gSp[i * 4 + (b - 3)] : (float)np;
    const float H  = baseH  + (float)(int)gA[i * AROW + b]  * INV64K;
    const float Hp = basePp + (float)(int)gAp[i * AROW + b] * INV64K;
    const float hp = Hp - HpPrev;
    HpPrev = Hp;
    if (H > 1e-6f) ap += hp * Hp / H;
  }
  if (np > 0) { ap /= (float)np; val = 1.f; } else ap = 0.f;

  __shared__ float sa[256], sv[256];
  sa[threadIdx.x] = ap; sv[threadIdx.x] = val;
  __syncthreads();
  for (int s = 128; s > 0; s >>= 1) {
    if (threadIdx.x < s) {
      sa[threadIdx.x] += sa[threadIdx.x + s];
      sv[threadIdx.x] += sv[threadIdx.x + s];
    }
    __syncthreads();
  }
  if (threadIdx.x == 0) {
    atomicAdd(&accum[0], sa[0]);
    atomicAdd(&accum[1], sv[0]);
    __threadfence();
    const unsigned prev = atomicAdd(done, 1u);
    if (prev == gridDim.x - 1) {
      const float a = atomicAdd(&accum[0], 0.f);   // coherent reads
      const float c = atomicAdd(&accum[1], 0.f);
      out[0] = 1.f - (c > 0.f ? a / c : 0.f);
    }
  }
}

extern "C" void kernel_launch(void* const* d_in, const int* in_sizes, int n_in,
                              void* d_out, int out_size, void* d_ws, size_t ws_size,
                              hipStream_t stream) {
  const float* x      = (const float*)d_in[0];
  const int*   labels = (const int*)d_in[1];
  float* out = (float*)d_out;

  char* ws = (char*)d_ws;
  unsigned short* xb = (unsigned short*)(ws + OFF_XB);
  float*    gS   = (float*)(ws + OFF_GS);
  float*    gSp  = (float*)(ws + OFF_GSP);
  unsigned* gA   = (unsigned*)(ws + OFF_GA);
  unsigned* gAp  = (unsigned*)(ws + OFF_GAP);
  int*      cc   = (int*)(ws + OFF_CC);
  float*    accum = (float*)(ws + OFF_AC);
  unsigned* done  = (unsigned*)(ws + OFF_AC + 8);

  prep_kernel<<<(NS * EMBED / 4) / 256, 256, 0, stream>>>(x, xb, (uint4*)(ws + OFF_GS));
  fastap_main_kernel<<<dim3(NS / 64, NS / COLCHUNK), 256, 0, stream>>>(
      xb, labels, gS, gSp, gA, gAp, cc);
  epilogue_kernel<<<NS / 256, 256, 0, stream>>>(gS, gSp, gA, gAp, labels, cc,
                                                accum, done, out);
}

// Round 6
// 141.419 us; speedup vs baseline: 1.6870x; 1.6870x over previous
//
#include <hip/hip_runtime.h>

#define NS 8192
#define EMBED 128
#define COLCHUNK 1024            // grid.y = 8 chunks of 1024 cols
#define AROW 12                  // adj-hist row stride (11 bins + 1 pad)
#define INV64K (1.0f / 65536.0f)

typedef __bf16 bf16x8 __attribute__((ext_vector_type(8)));
typedef float f32x4 __attribute__((ext_vector_type(4)));
typedef const __attribute__((address_space(1))) unsigned ag_u32;  // global
typedef __attribute__((address_space(3))) unsigned al_u32;        // LDS

// workspace layout (bytes from ws start)
#define OFF_XB  0u               // bf16 [8192][128] = 2 MiB (row-granule-XOR-swizzled)
#define OFF_GS  2097152u         // fp32 [8192][4]   cumulative C bins 3..6
#define OFF_GSP 2228224u         // fp32 [8192][4]   cumulative Cp bins 3..6
#define OFF_GA  2359296u         // i32  [8192][12]  all-hist corrections (q16)
#define OFF_GAP 2752512u         // i32  [8192][12]  pos-hist corrections (q16)
#define OFF_CC  3145728u         // int  [128] class counts
#define OFF_AC  3146240u         // float[2] accum + u32 done
#define ZERO_BYTES 1049120u      // OFF_GS .. end (16B multiple)

__device__ inline unsigned short f2bf(float f) {
  unsigned u = __float_as_uint(f);
  u += 0x7fffu + ((u >> 16) & 1u);   // round-to-nearest-even
  return (unsigned short)(u >> 16);
}
__device__ inline float clamp01(float x) { return fminf(fmaxf(x, 0.f), 1.f); }

// ---- prep: fp32->bf16 convert into XOR-swizzled layout + zero accumulators ----
// Row r's sixteen 16B granules are stored at physical slot g^(r&7), so the main
// kernel's LINEAR global_load_lds staging still gives conflict-free ds_read_b128.
__global__ __launch_bounds__(256) void prep_kernel(const float* __restrict__ x,
                                                   unsigned short* __restrict__ xb,
                                                   uint4* __restrict__ zbase) {
  const int gid = blockIdx.x * 256 + threadIdx.x;   // 131072 threads: row*16+granule
  const int row = gid >> 4, g = gid & 15;
  const float4 v0 = reinterpret_cast<const float4*>(x)[row * 32 + g * 2];
  const float4 v1 = reinterpret_cast<const float4*>(x)[row * 32 + g * 2 + 1];
  uint4 o;
  o.x = (unsigned)f2bf(v0.x) | ((unsigned)f2bf(v0.y) << 16);
  o.y = (unsigned)f2bf(v0.z) | ((unsigned)f2bf(v0.w) << 16);
  o.z = (unsigned)f2bf(v1.x) | ((unsigned)f2bf(v1.y) << 16);
  o.w = (unsigned)f2bf(v1.z) | ((unsigned)f2bf(v1.w) << 16);
  reinterpret_cast<uint4*>(xb)[row * 16 + (g ^ (row & 7))] = o;
  if (gid < (int)(ZERO_BYTES / 16u)) zbase[gid] = make_uint4(0u, 0u, 0u, 0u);
}

// ---- main: LDS-double-buffered B staging (async) + MFMA + register hist ----
__global__ __launch_bounds__(256, 4) void fastap_main_kernel(
    const unsigned short* __restrict__ xb,
    const int* __restrict__ labels,
    float* __restrict__ gS, float* __restrict__ gSp,
    unsigned* __restrict__ gA, unsigned* __restrict__ gAp,
    int* __restrict__ ccount) {
  __shared__ __align__(16) unsigned short sB[2][16 * 128];  // 2 x 4KB B panels
  __shared__ int sLab[COLCHUNK];
  __shared__ unsigned sHs[64 * AROW];   // all-hist corrections (signed q16)
  __shared__ unsigned sHsp[64 * AROW];  // pos-hist corrections (signed q16)

  const int tid  = threadIdx.x;
  const int wave = tid >> 6;
  const int lane = tid & 63;
  const int l16  = lane & 15;
  const int quad = lane >> 4;
  const int rowBase  = blockIdx.x * 64;
  const int colBegin = blockIdx.y * COLCHUNK;
  const int rl0 = wave * 16 + quad * 4;

  if (blockIdx.y == 0 && tid < 64) atomicAdd(&ccount[labels[rowBase + tid]], 1);

  reinterpret_cast<int4*>(sLab)[tid] =
      reinterpret_cast<const int4*>(labels + colBegin)[tid];
  for (int i = tid; i < 64 * AROW; i += 256) { sHs[i] = 0u; sHsp[i] = 0u; }

  // A fragments from swizzled xb: logical granule kb*4+quad at phys ^(arow&7)
  bf16x8 afr[4];
  const int arow = rowBase + wave * 16 + l16;
  #pragma unroll
  for (int kb = 0; kb < 4; ++kb) {
    const int pg = (kb * 4 + quad) ^ (arow & 7);
    afr[kb] = *reinterpret_cast<const bf16x8*>(&xb[arow * 128 + pg * 8]);
  }

  int labi[4], iRow[4];
  #pragma unroll
  for (int r = 0; r < 4; ++r) {
    iRow[r] = rowBase + rl0 + r;
    labi[r] = labels[iRow[r]];
  }

  float C[4][4], Cp[4][4];
  #pragma unroll
  for (int r = 0; r < 4; ++r)
    #pragma unroll
    for (int k = 0; k < 4; ++k) { C[r][k] = 0.f; Cp[r][k] = 0.f; }

  // loop-invariant ds_read offsets (ushort units): col l16, granule swizzled by
  // (ct+l16)&7 == l16&7 since ct is a multiple of 16.
  int bOff[4];
  #pragma unroll
  for (int kb = 0; kb < 4; ++kb)
    bOff[kb] = l16 * 128 + (((kb * 4 + quad) ^ (l16 & 7)) << 3);

  // per-thread staging addresses: thread t copies 16B granule (t&15) of panel
  // col (t>>4); LDS dst = tid*16 (wave-uniform base + lane*16 as required).
  const unsigned short* srcT = xb + (colBegin + (tid >> 4)) * 128 + (tid & 15) * 8;
  unsigned short* dst0 = &sB[0][tid * 8];
  unsigned short* dst1 = &sB[1][tid * 8];

  auto process16 = [&](const unsigned short* bufp, int c0, bool doPref,
                       const unsigned short* psrc, unsigned short* pdst) {
    __syncthreads();   // drains the async stage of THIS tile's panel
    if (doPref)        // kick next tile's panel while we compute
      __builtin_amdgcn_global_load_lds((ag_u32*)psrc, (al_u32*)pdst, 16, 0, 0);
    const int labj = sLab[c0 + l16];
    const int j = colBegin + c0 + l16;           // C/D: col = lane&15
    const bf16x8 b0 = *reinterpret_cast<const bf16x8*>(&bufp[bOff[0]]);
    const bf16x8 b1 = *reinterpret_cast<const bf16x8*>(&bufp[bOff[1]]);
    const bf16x8 b2 = *reinterpret_cast<const bf16x8*>(&bufp[bOff[2]]);
    const bf16x8 b3 = *reinterpret_cast<const bf16x8*>(&bufp[bOff[3]]);
    f32x4 acc0 = {0.f, 0.f, 0.f, 0.f}, acc1 = {0.f, 0.f, 0.f, 0.f};
    acc0 = __builtin_amdgcn_mfma_f32_16x16x32_bf16(afr[0], b0, acc0, 0, 0, 0);
    acc0 = __builtin_amdgcn_mfma_f32_16x16x32_bf16(afr[1], b1, acc0, 0, 0, 0);
    acc1 = __builtin_amdgcn_mfma_f32_16x16x32_bf16(afr[2], b2, acc1, 0, 0, 0);
    acc1 = __builtin_amdgcn_mfma_f32_16x16x32_bf16(afr[3], b3, acc1, 0, 0, 0);

    #pragma unroll
    for (int r = 0; r < 4; ++r) {                // C/D: row = quad*4 + reg
      const float a = acc0[r] + acc1[r];         // cos;  u = t-5 = -5a
      const bool isPos = (labi[r] == labj) & (iRow[r] != j);
      const float pm = isPos ? 1.f : 0.f;
      const float d0 = clamp01(fmaf(a, 5.f, -1.f));   // bin 3
      const float d1 = clamp01(a * 5.f);              // bin 4
      const float d2 = clamp01(fmaf(a, 5.f, 1.f));    // bin 5
      const float d3 = clamp01(fmaf(a, 5.f, 2.f));    // bin 6
      C[r][0] += d0; C[r][1] += d1; C[r][2] += d2; C[r][3] += d3;
      Cp[r][0] = fmaf(pm, d0, Cp[r][0]);
      Cp[r][1] = fmaf(pm, d1, Cp[r][1]);
      Cp[r][2] = fmaf(pm, d2, Cp[r][2]);
      Cp[r][3] = fmaf(pm, d3, Cp[r][3]);

      if (fabsf(a) > 0.4f) {                     // rare: outlier or diagonal
        const int row = rl0 + r;
        if (iRow[r] == j) {
          C[r][0] -= d0; C[r][1] -= d1; C[r][2] -= d2; C[r][3] -= d3;
          #pragma unroll
          for (int k = 7; k <= 10; ++k)
            atomicAdd(&sHs[row * AROW + k], (unsigned)(-65536));
        } else {
          const float t = fmaf(a, -5.f, 5.f);
          #pragma unroll
          for (int k = 0; k <= 2; ++k) {         // assumed cumulative 0
            const float v = clamp01((float)(k + 1) - t);
            const int q = (int)(v * 65536.f + 0.5f);
            if (q) {
              atomicAdd(&sHs[row * AROW + k], (unsigned)q);
              if (isPos) atomicAdd(&sHsp[row * AROW + k], (unsigned)q);
            }
          }
          #pragma unroll
          for (int k = 7; k <= 10; ++k) {        // assumed cumulative 1
            const float v = clamp01((float)(k + 1) - t) - 1.f;
            const int q = (int)(v * 65536.f - 0.5f);
            if (q) {
              atomicAdd(&sHs[row * AROW + k], (unsigned)q);
              if (isPos) atomicAdd(&sHsp[row * AROW + k], (unsigned)q);
            }
          }
        }
      }
    }
  };

  // prime buffer 0 with tile 0
  __builtin_amdgcn_global_load_lds((ag_u32*)srcT, (al_u32*)dst0, 16, 0, 0);

  for (int c0 = 0; c0 < COLCHUNK; c0 += 32) {
    process16(sB[0], c0,      true,               srcT + (c0 + 16) * 128, dst1);
    process16(sB[1], c0 + 16, (c0 + 32) < COLCHUNK, srcT + (c0 + 32) * 128, dst0);
  }

  // butterfly-reduce C/Cp across the 16 lanes sharing each row
  #pragma unroll
  for (int m = 1; m < 16; m <<= 1)
    #pragma unroll
    for (int r = 0; r < 4; ++r)
      #pragma unroll
      for (int k = 0; k < 4; ++k) {
        C[r][k]  += __shfl_xor(C[r][k],  m, 64);
        Cp[r][k] += __shfl_xor(Cp[r][k], m, 64);
      }

  if (l16 == 0) {
    #pragma unroll
    for (int r = 0; r < 4; ++r)
      #pragma unroll
      for (int k = 0; k < 4; ++k) {
        atomicAdd(&gS[(rowBase + rl0 + r) * 4 + k],  C[r][k]);
        atomicAdd(&gSp[(rowBase + rl0 + r) * 4 + k], Cp[r][k]);
      }
  }

  __syncthreads();
  for (int idx = tid; idx < 64 * AROW; idx += 256) {
    const unsigned v = sHs[idx], vp = sHsp[idx];
    if (v)  atomicAdd(&gA[rowBase * AROW + idx], v);
    if (vp) atomicAdd(&gAp[rowBase * AROW + idx], vp);
  }
}

// ---- epilogue: per-row AP + final loss (last block finalizes) ----
__global__ __launch_bounds__(256) void epilogue_kernel(
    const float* __restrict__ gS, const float* __restrict__ gSp,
    const unsigned* __restrict__ gA, const unsigned* __restrict__ gAp,
    const int* __restrict__ labels, const int* __restrict__ ccount,
    float* __restrict__ accum, unsigned* __restrict__ done,
    float* __restrict__ out) {
  const int i = blockIdx.x * 256 + threadIdx.x;
  const int np = ccount[labels[i]] - 1;   // N_pos = classCount - 1
  float ap = 0.f, val = 0.f, HpPrev = 0.f;
  #pragma unroll
  for (int b = 0; b <= 10; ++b) {
    const float baseH  = (b < 3) ? 0.f : (b < 7) ? gS[i * 4 + (b - 3)]  : 8192.f;
    const float basePp = (b < 3) ? 0.f : (b < 7) ? gSp[i * 4 + (b - 3)] : (float)np;
    const float H  = baseH  + (float)(int)gA[i * AROW + b]  * INV64K;
    const float Hp = basePp + (float)(int)gAp[i * AROW + b] * INV64K;
    const float hp = Hp - HpPrev;
    HpPrev = Hp;
    if (H > 1e-6f) ap += hp * Hp / H;
  }
  if (np > 0) { ap /= (float)np; val = 1.f; } else ap = 0.f;

  __shared__ float sa[256], sv[256];
  sa[threadIdx.x] = ap; sv[threadIdx.x] = val;
  __syncthreads();
  for (int s = 128; s > 0; s >>= 1) {
    if (threadIdx.x < s) {
      sa[threadIdx.x] += sa[threadIdx.x + s];
      sv[threadIdx.x] += sv[threadIdx.x + s];
    }
    __syncthreads();
  }
  if (threadIdx.x == 0) {
    atomicAdd(&accum[0], sa[0]);
    atomicAdd(&accum[1], sv[0]);
    __threadfence();
    const unsigned prev = atomicAdd(done, 1u);
    if (prev == gridDim.x - 1) {
      const float a = atomicAdd(&accum[0], 0.f);   // coherent reads
      const float c = atomicAdd(&accum[1], 0.f);
      out[0] = 1.f - (c > 0.f ? a / c : 0.f);
    }
  }
}

extern "C" void kernel_launch(void* const* d_in, const int* in_sizes, int n_in,
                              void* d_out, int out_size, void* d_ws, size_t ws_size,
                              hipStream_t stream) {
  const float* x      = (const float*)d_in[0];
  const int*   labels = (const int*)d_in[1];
  float* out = (float*)d_out;

  char* ws = (char*)d_ws;
  unsigned short* xb = (unsigned short*)(ws + OFF_XB);
  float*    gS   = (float*)(ws + OFF_GS);
  float*    gSp  = (float*)(ws + OFF_GSP);
  unsigned* gA   = (unsigned*)(ws + OFF_GA);
  unsigned* gAp  = (unsigned*)(ws + OFF_GAP);
  int*      cc   = (int*)(ws + OFF_CC);
  float*    accum = (float*)(ws + OFF_AC);
  unsigned* done  = (unsigned*)(ws + OFF_AC + 8);

  prep_kernel<<<512, 256, 0, stream>>>(x, xb, (uint4*)(ws + OFF_GS));
  fastap_main_kernel<<<dim3(NS / 64, NS / COLCHUNK), 256, 0, stream>>>(
      xb, labels, gS, gSp, gA, gAp, cc);
  epilogue_kernel<<<NS / 256, 256, 0, stream>>>(gS, gSp, gA, gAp, labels, cc,
                                                accum, done, out);
}